// Round 1
// baseline (737.277 us; speedup 1.0000x reference)
//
#include <hip/hip_runtime.h>

#define NEG_SLOPE 0.01f

__device__ __forceinline__ float lrelu(float v) { return v > 0.f ? v : NEG_SLOPE * v; }

// order-preserving float -> unsigned map for atomicMax
__device__ __forceinline__ unsigned fkey(float f) {
    unsigned b = __float_as_uint(f);
    return (b & 0x80000000u) ? ~b : (b | 0x80000000u);
}
__device__ __forceinline__ float fdec(unsigned k) {
    unsigned b = (k & 0x80000000u) ? (k ^ 0x80000000u) : ~k;
    return __uint_as_float(b);
}

__device__ __forceinline__ float waveReduceSum(float v) {
#pragma unroll
    for (int m = 1; m < 64; m <<= 1) v += __shfl_xor(v, m, 64);
    return v;
}

// one wave per node: alpha_node[d] = lrelu( sum_k x[d][k]*lsa[batch[d]][k]*Wa[k] )
__global__ void alpha_kernel(const float2* __restrict__ x2, const float2* __restrict__ lsa2,
                             const float2* __restrict__ Wa2, const int* __restrict__ batch,
                             float* __restrict__ alpha_node, int N) {
    int node = (blockIdx.x * blockDim.x + threadIdx.x) >> 6;
    int lane = threadIdx.x & 63;
    if (node >= N) return;
    int b = batch[node];
    float2 xv = x2[(long long)node * 64 + lane];
    float2 qv = lsa2[(long long)b * 64 + lane];
    float2 wv = Wa2[lane];
    float p = xv.x * qv.x * wv.x + xv.y * qv.y * wv.y;
    p = waveReduceSum(p);
    if (lane == 0) alpha_node[node] = lrelu(p);
}

// one wave per expanded edge: logit = lrelu(dot(x[d]*x[s], W)) + alpha_node[d]
__global__ void logits_kernel(const float2* __restrict__ x2,
                              const int* __restrict__ EI0, const int* __restrict__ EI1,
                              const float2* __restrict__ Wf2, const float2* __restrict__ Wb2,
                              const float* __restrict__ alpha_node,
                              float* __restrict__ logits, unsigned* __restrict__ segmax,
                              int E_total, int E_NS) {
    long long gid = (long long)blockIdx.x * blockDim.x + threadIdx.x;
    int e = (int)(gid >> 6);
    int lane = threadIdx.x & 63;
    int EE = E_total + E_NS;
    if (e >= EE) return;
    int s, d;
    const float2* W2;
    if (e < E_total) { s = EI0[e]; d = EI1[e]; W2 = Wf2; }
    else { int e2 = e - E_total; s = EI1[e2]; d = EI0[e2]; W2 = Wb2; }
    float2 xs = x2[(long long)s * 64 + lane];
    float2 xd = x2[(long long)d * 64 + lane];
    float2 wv = W2[lane];
    float p = xs.x * xd.x * wv.x + xs.y * xd.y * wv.y;
    p = waveReduceSum(p);
    if (lane == 0) {
        float logit = lrelu(p) + alpha_node[d];
        logits[e] = logit;
        atomicMax(&segmax[d], fkey(logit));
    }
}

// one thread per edge: ex = exp(logit - segmax[d]); denom[d] += ex (in-place over logits)
__global__ void ex_kernel(const int* __restrict__ EI0, const int* __restrict__ EI1,
                          float* __restrict__ logits, const unsigned* __restrict__ segmax,
                          float* __restrict__ denom, int E_total, int E_NS) {
    int e = blockIdx.x * blockDim.x + threadIdx.x;
    int EE = E_total + E_NS;
    if (e >= EE) return;
    int d = (e < E_total) ? EI1[e] : EI0[e - E_total];
    float m = fdec(segmax[d]);
    float ex = __expf(logits[e] - m);
    logits[e] = ex;
    atomicAdd(&denom[d], ex);
}

// one wave per edge: out[d] += (ex/denom[d]) * x[s]
__global__ void scatter_kernel(const float2* __restrict__ x2,
                               const int* __restrict__ EI0, const int* __restrict__ EI1,
                               const float* __restrict__ ex, const float* __restrict__ denom,
                               float* __restrict__ out, int E_total, int E_NS) {
    long long gid = (long long)blockIdx.x * blockDim.x + threadIdx.x;
    int e = (int)(gid >> 6);
    int lane = threadIdx.x & 63;
    int EE = E_total + E_NS;
    if (e >= EE) return;
    int s, d;
    if (e < E_total) { s = EI0[e]; d = EI1[e]; }
    else { int e2 = e - E_total; s = EI1[e2]; d = EI0[e2]; }
    float w = ex[e] / denom[d];
    float2 xv = x2[(long long)s * 64 + lane];
    float* dst = out + (long long)d * 128 + 2 * lane;
    atomicAdd(dst, w * xv.x);
    atomicAdd(dst + 1, w * xv.y);
}

// out[i] = mask ? aggr + x : 2x
__global__ void final_kernel(const float* __restrict__ x, const int* __restrict__ mask,
                             float* __restrict__ out, int ND) {
    int i = blockIdx.x * blockDim.x + threadIdx.x;
    if (i >= ND) return;
    int node = i >> 7;
    float xv = x[i];
    out[i] = (mask[node] == 1) ? (out[i] + xv) : (xv + xv);
}

extern "C" void kernel_launch(void* const* d_in, const int* in_sizes, int n_in,
                              void* d_out, int out_size, void* d_ws, size_t ws_size,
                              hipStream_t stream) {
    const float* x   = (const float*)d_in[0];
    const float* Wa  = (const float*)d_in[1];
    const float* Wf  = (const float*)d_in[2];
    const float* Wb  = (const float*)d_in[3];
    const float* lsa = (const float*)d_in[4];
    const int* EI    = (const int*)d_in[5];
    const int* batch = (const int*)d_in[6];
    const int* mask  = (const int*)d_in[7];

    int N = in_sizes[6];             // 50000
    int E_total = in_sizes[5] / 2;   // 300000 (non-self + self loops)
    int E_NS = E_total - N;          // 250000
    int EE = E_total + E_NS;         // 550000 expanded edges
    int ND = out_size;               // N*128

    const int* EI0 = EI;             // row 0: src (+ loops)
    const int* EI1 = EI + E_total;   // row 1: dst (+ loops)

    char* ws = (char*)d_ws;
    unsigned* segmax  = (unsigned*)ws;                       // N
    float* denom      = (float*)(ws + (size_t)N * 4);        // N
    float* alpha_node = (float*)(ws + (size_t)2 * N * 4);    // N
    float* logits     = (float*)(ws + (size_t)3 * N * 4);    // EE (reused as ex)

    hipMemsetAsync(segmax, 0, (size_t)N * 4, stream);
    hipMemsetAsync(denom, 0, (size_t)N * 4, stream);
    hipMemsetAsync(d_out, 0, (size_t)out_size * 4, stream);

    const int BLK = 256;
    int nodeWaveBlocks = (N + 3) / 4;     // 4 waves (nodes) per 256-thread block
    int edgeWaveBlocks = (EE + 3) / 4;    // 4 waves (edges) per block
    int edgeThreadBlocks = (EE + BLK - 1) / BLK;
    int ndBlocks = (ND + BLK - 1) / BLK;

    alpha_kernel<<<nodeWaveBlocks, BLK, 0, stream>>>(
        (const float2*)x, (const float2*)lsa, (const float2*)Wa, batch, alpha_node, N);

    logits_kernel<<<edgeWaveBlocks, BLK, 0, stream>>>(
        (const float2*)x, EI0, EI1, (const float2*)Wf, (const float2*)Wb,
        alpha_node, logits, segmax, E_total, E_NS);

    ex_kernel<<<edgeThreadBlocks, BLK, 0, stream>>>(
        EI0, EI1, logits, segmax, denom, E_total, E_NS);

    scatter_kernel<<<edgeWaveBlocks, BLK, 0, stream>>>(
        (const float2*)x, EI0, EI1, logits, denom, (float*)d_out, E_total, E_NS);

    final_kernel<<<ndBlocks, BLK, 0, stream>>>(x, mask, (float*)d_out, ND);
}

// Round 2
// 228.452 us; speedup vs baseline: 3.2273x; 3.2273x over previous
//
#include <hip/hip_runtime.h>

#define NEG_SLOPE 0.01f

__device__ __forceinline__ float lrelu(float v) { return v > 0.f ? v : NEG_SLOPE * v; }

__device__ __forceinline__ float waveReduceSum(float v) {
#pragma unroll
    for (int m = 1; m < 64; m <<= 1) v += __shfl_xor(v, m, 64);
    return v;
}

// --- CSR build -------------------------------------------------------------

// count incoming expanded edges per destination node
__global__ void count_kernel(const int* __restrict__ EI0, const int* __restrict__ EI1,
                             int* __restrict__ counts, int E_total, int E_NS) {
    int e = blockIdx.x * blockDim.x + threadIdx.x;
    int EE = E_total + E_NS;
    if (e >= EE) return;
    int d = (e < E_total) ? EI1[e] : EI0[e - E_total];
    atomicAdd(&counts[d], 1);
}

// block-local exclusive scan (256/block); rowptr gets local-exclusive, blockSums gets block total
__global__ void scan1_kernel(const int* __restrict__ counts, int* __restrict__ rowptr,
                             int* __restrict__ blockSums, int N) {
    __shared__ int tmp[256];
    int tid = threadIdx.x;
    int gid = blockIdx.x * 256 + tid;
    int v = (gid < N) ? counts[gid] : 0;
    tmp[tid] = v;
    __syncthreads();
#pragma unroll
    for (int off = 1; off < 256; off <<= 1) {
        int t = (tid >= off) ? tmp[tid - off] : 0;
        __syncthreads();
        tmp[tid] += t;
        __syncthreads();
    }
    if (gid < N) rowptr[gid] = tmp[tid] - v;
    if (tid == 255) blockSums[blockIdx.x] = tmp[255];
}

// exclusive scan of block sums (nb <= 256), in place
__global__ void scan2_kernel(int* __restrict__ blockSums, int nb) {
    __shared__ int tmp[256];
    int tid = threadIdx.x;
    int v = (tid < nb) ? blockSums[tid] : 0;
    tmp[tid] = v;
    __syncthreads();
#pragma unroll
    for (int off = 1; off < 256; off <<= 1) {
        int t = (tid >= off) ? tmp[tid - off] : 0;
        __syncthreads();
        tmp[tid] += t;
        __syncthreads();
    }
    if (tid < nb) blockSums[tid] = tmp[tid] - v;
}

// add block offsets -> global exclusive scan
__global__ void scan3_kernel(int* __restrict__ rowptr, const int* __restrict__ blockSums, int N) {
    int gid = blockIdx.x * 256 + threadIdx.x;
    if (gid < N) rowptr[gid] += blockSums[blockIdx.x];
}

// place each expanded edge into its destination's CSR segment; bit31 = use-W_backward flag
__global__ void fill_kernel(const int* __restrict__ EI0, const int* __restrict__ EI1,
                            const int* __restrict__ rowptr, int* __restrict__ cursor,
                            int* __restrict__ csr, int E_total, int E_NS) {
    int e = blockIdx.x * blockDim.x + threadIdx.x;
    int EE = E_total + E_NS;
    if (e >= EE) return;
    int s, d, flag;
    if (e < E_total) { s = EI0[e]; d = EI1[e]; flag = 0; }
    else { int e2 = e - E_total; s = EI1[e2]; d = EI0[e2]; flag = 1; }
    int pos = atomicAdd(&cursor[d], 1);
    csr[rowptr[d] + pos] = s | (flag << 31);
}

// --- fused gather: online segment-softmax + weighted aggregation + residual ---
// one wave per destination node; alpha term cancels (constant per segment)
__global__ void gather_kernel(const float2* __restrict__ x2,
                              const float2* __restrict__ Wf2, const float2* __restrict__ Wb2,
                              const int* __restrict__ rowptr, const int* __restrict__ counts,
                              const int* __restrict__ csr, const int* __restrict__ mask,
                              float2* __restrict__ out2, int N) {
    int node = (blockIdx.x * blockDim.x + threadIdx.x) >> 6;
    int lane = threadIdx.x & 63;
    if (node >= N) return;

    float2 xd = x2[(long long)node * 64 + lane];

    if (mask[node] != 1) {
        float2 res = {2.f * xd.x, 2.f * xd.y};
        out2[(long long)node * 64 + lane] = res;
        return;
    }

    float2 wf = Wf2[lane];
    float2 wb = Wb2[lane];
    int beg = rowptr[node];
    int cnt = counts[node];

    float m = -INFINITY, l = 0.f;
    float2 O = {0.f, 0.f};

    int entry = (cnt > 0) ? csr[beg] : 0;
    float2 xs = {0.f, 0.f};
    if (cnt > 0) xs = x2[(long long)(entry & 0x7fffffff) * 64 + lane];

    for (int i = 0; i < cnt; i++) {
        unsigned flag = ((unsigned)entry) >> 31;
        float2 xcur = xs;
        int nentry = 0;
        if (i + 1 < cnt) {  // prefetch next src row while we reduce
            nentry = csr[beg + i + 1];
            xs = x2[(long long)(nentry & 0x7fffffff) * 64 + lane];
        }
        float2 wv = flag ? wb : wf;
        float p = xcur.x * xd.x * wv.x + xcur.y * xd.y * wv.y;
        p = waveReduceSum(p);
        float logit = lrelu(p);
        float mn = fmaxf(m, logit);
        float sc = __expf(m - mn);      // first iter: exp(-inf)=0
        float ev = __expf(logit - mn);
        l = l * sc + ev;
        O.x = O.x * sc + ev * xcur.x;
        O.y = O.y * sc + ev * xcur.y;
        m = mn;
        entry = nentry;
    }

    float inv = (l > 0.f) ? 1.f / l : 0.f;
    float2 res = {O.x * inv + xd.x, O.y * inv + xd.y};
    out2[(long long)node * 64 + lane] = res;
}

extern "C" void kernel_launch(void* const* d_in, const int* in_sizes, int n_in,
                              void* d_out, int out_size, void* d_ws, size_t ws_size,
                              hipStream_t stream) {
    const float* x   = (const float*)d_in[0];
    const float* Wf  = (const float*)d_in[2];
    const float* Wb  = (const float*)d_in[3];
    const int* EI    = (const int*)d_in[5];
    const int* mask  = (const int*)d_in[7];
    // d_in[1] (W_alpha), d_in[4] (local_sess_avg), d_in[6] (batch) are dead:
    // alpha is constant within each softmax segment and cancels exactly.

    int N = in_sizes[6];             // 50000
    int E_total = in_sizes[5] / 2;   // 300000 (non-self + self loops)
    int E_NS = E_total - N;          // 250000
    int EE = E_total + E_NS;         // 550000 expanded edges

    const int* EI0 = EI;             // row 0: src (+ loops)
    const int* EI1 = EI + E_total;   // row 1: dst (+ loops)

    char* ws = (char*)d_ws;
    int* counts    = (int*)ws;                               // N
    int* rowptr    = (int*)(ws + (size_t)N * 4);             // N
    int* cursor    = (int*)(ws + (size_t)2 * N * 4);         // N
    int* blockSums = (int*)(ws + (size_t)3 * N * 4);         // 256
    int* csr       = (int*)(ws + (size_t)3 * N * 4 + 1024);  // EE

    hipMemsetAsync(counts, 0, (size_t)N * 4, stream);
    hipMemsetAsync(cursor, 0, (size_t)N * 4, stream);

    const int BLK = 256;
    int edgeBlocks = (EE + BLK - 1) / BLK;
    int scanBlocks = (N + BLK - 1) / BLK;   // 196 <= 256, fits scan2's single block
    int nodeWaveBlocks = (N + 3) / 4;       // 4 waves (nodes) per 256-thread block

    count_kernel<<<edgeBlocks, BLK, 0, stream>>>(EI0, EI1, counts, E_total, E_NS);
    scan1_kernel<<<scanBlocks, BLK, 0, stream>>>(counts, rowptr, blockSums, N);
    scan2_kernel<<<1, BLK, 0, stream>>>(blockSums, scanBlocks);
    scan3_kernel<<<scanBlocks, BLK, 0, stream>>>(rowptr, blockSums, N);
    fill_kernel<<<edgeBlocks, BLK, 0, stream>>>(EI0, EI1, rowptr, cursor, csr, E_total, E_NS);

    gather_kernel<<<nodeWaveBlocks, BLK, 0, stream>>>(
        (const float2*)x, (const float2*)Wf, (const float2*)Wb,
        rowptr, counts, csr, mask, (float2*)d_out, N);
}

// Round 3
// 197.293 us; speedup vs baseline: 3.7370x; 1.1579x over previous
//
#include <hip/hip_runtime.h>

#define NEG_SLOPE 0.01f

__device__ __forceinline__ float lrelu(float v) { return v > 0.f ? v : NEG_SLOPE * v; }

// --- CSR build -------------------------------------------------------------

__global__ void count_kernel(const int* __restrict__ EI0, const int* __restrict__ EI1,
                             int* __restrict__ counts, int E_total, int E_NS) {
    int e = blockIdx.x * blockDim.x + threadIdx.x;
    int EE = E_total + E_NS;
    if (e >= EE) return;
    int d = (e < E_total) ? EI1[e] : EI0[e - E_total];
    atomicAdd(&counts[d], 1);
}

// block-local exclusive scan (256/block); rowptrL gets local-exclusive, blockSums gets block total
__global__ void scan1_kernel(const int* __restrict__ counts, int* __restrict__ rowptrL,
                             int* __restrict__ blockSums, int N) {
    __shared__ int tmp[256];
    int tid = threadIdx.x;
    int gid = blockIdx.x * 256 + tid;
    int v = (gid < N) ? counts[gid] : 0;
    tmp[tid] = v;
    __syncthreads();
#pragma unroll
    for (int off = 1; off < 256; off <<= 1) {
        int t = (tid >= off) ? tmp[tid - off] : 0;
        __syncthreads();
        tmp[tid] += t;
        __syncthreads();
    }
    if (gid < N) rowptrL[gid] = tmp[tid] - v;
    if (tid == 255) blockSums[blockIdx.x] = tmp[255];
}

// exclusive scan of block sums (nb <= 256), in place
__global__ void scan2_kernel(int* __restrict__ blockSums, int nb) {
    __shared__ int tmp[256];
    int tid = threadIdx.x;
    int v = (tid < nb) ? blockSums[tid] : 0;
    tmp[tid] = v;
    __syncthreads();
#pragma unroll
    for (int off = 1; off < 256; off <<= 1) {
        int t = (tid >= off) ? tmp[tid - off] : 0;
        __syncthreads();
        tmp[tid] += t;
        __syncthreads();
    }
    if (tid < nb) blockSums[tid] = tmp[tid] - v;
}

// place each edge into its destination's CSR segment; global offset = local + blockSums[d>>8]
__global__ void fill_kernel(const int* __restrict__ EI0, const int* __restrict__ EI1,
                            const int* __restrict__ rowptrL, const int* __restrict__ blockSums,
                            int* __restrict__ cursor, int* __restrict__ csr,
                            int E_total, int E_NS) {
    int e = blockIdx.x * blockDim.x + threadIdx.x;
    int EE = E_total + E_NS;
    if (e >= EE) return;
    int s, d, flag;
    if (e < E_total) { s = EI0[e]; d = EI1[e]; flag = 0; }
    else { int e2 = e - E_total; s = EI1[e2]; d = EI0[e2]; flag = 1; }
    int pos = atomicAdd(&cursor[d], 1);
    csr[rowptrL[d] + blockSums[d >> 8] + pos] = s | (flag << 31);
}

// --- fused gather: 4-deep edge-batched online softmax + aggregation + residual ---
__global__ void gather_kernel(const float2* __restrict__ x2,
                              const float2* __restrict__ Wf2, const float2* __restrict__ Wb2,
                              const int* __restrict__ rowptrL, const int* __restrict__ blockSums,
                              const int* __restrict__ counts, const int* __restrict__ csr,
                              const int* __restrict__ mask,
                              float2* __restrict__ out2, int N) {
    int node = (blockIdx.x * blockDim.x + threadIdx.x) >> 6;
    int lane = threadIdx.x & 63;
    if (node >= N) return;

    float2 xd = x2[(long long)node * 64 + lane];

    if (mask[node] != 1) {
        float2 res = {2.f * xd.x, 2.f * xd.y};
        out2[(long long)node * 64 + lane] = res;
        return;
    }

    float2 wf = Wf2[lane];
    float2 wb = Wb2[lane];
    float2 yf = {xd.x * wf.x, xd.y * wf.y};   // x[d] ⊙ Wf
    float2 yb = {xd.x * wb.x, xd.y * wb.y};   // x[d] ⊙ Wb

    int beg = rowptrL[node] + blockSums[node >> 8];
    int cnt = counts[node];

    float m = -INFINITY, l = 0.f;
    float2 O = {0.f, 0.f};

    for (int g = 0; g < cnt; g += 4) {
        int k = cnt - g; if (k > 4) k = 4;
        // 4 CSR entries (wave-uniform scalar loads)
        int e0 = csr[beg + g];
        int e1 = (k > 1) ? csr[beg + g + 1] : e0;
        int e2 = (k > 2) ? csr[beg + g + 2] : e0;
        int e3 = (k > 3) ? csr[beg + g + 3] : e0;
        // 4 row loads issued back-to-back -> 4 outstanding per wave
        float2 r0 = x2[(long long)(e0 & 0x7fffffff) * 64 + lane];
        float2 r1 = x2[(long long)(e1 & 0x7fffffff) * 64 + lane];
        float2 r2 = x2[(long long)(e2 & 0x7fffffff) * 64 + lane];
        float2 r3 = x2[(long long)(e3 & 0x7fffffff) * 64 + lane];

        float2 y0 = (((unsigned)e0) >> 31) ? yb : yf;
        float2 y1 = (((unsigned)e1) >> 31) ? yb : yf;
        float2 y2 = (((unsigned)e2) >> 31) ? yb : yf;
        float2 y3 = (((unsigned)e3) >> 31) ? yb : yf;

        float p0 = r0.x * y0.x + r0.y * y0.y;
        float p1 = r1.x * y1.x + r1.y * y1.y;
        float p2 = r2.x * y2.x + r2.y * y2.y;
        float p3 = r3.x * y3.x + r3.y * y3.y;

        // 4 interleaved reduce chains (4x ILP on the cross-lane tree)
#pragma unroll
        for (int sh = 1; sh < 64; sh <<= 1) {
            p0 += __shfl_xor(p0, sh, 64);
            p1 += __shfl_xor(p1, sh, 64);
            p2 += __shfl_xor(p2, sh, 64);
            p3 += __shfl_xor(p3, sh, 64);
        }

        // sequential (cheap) online-softmax updates
        {
            float lg = lrelu(p0);
            float mn = fmaxf(m, lg);
            float sc = __expf(m - mn), ev = __expf(lg - mn);
            l = l * sc + ev;
            O.x = O.x * sc + ev * r0.x;
            O.y = O.y * sc + ev * r0.y;
            m = mn;
        }
        if (k > 1) {
            float lg = lrelu(p1);
            float mn = fmaxf(m, lg);
            float sc = __expf(m - mn), ev = __expf(lg - mn);
            l = l * sc + ev;
            O.x = O.x * sc + ev * r1.x;
            O.y = O.y * sc + ev * r1.y;
            m = mn;
        }
        if (k > 2) {
            float lg = lrelu(p2);
            float mn = fmaxf(m, lg);
            float sc = __expf(m - mn), ev = __expf(lg - mn);
            l = l * sc + ev;
            O.x = O.x * sc + ev * r2.x;
            O.y = O.y * sc + ev * r2.y;
            m = mn;
        }
        if (k > 3) {
            float lg = lrelu(p3);
            float mn = fmaxf(m, lg);
            float sc = __expf(m - mn), ev = __expf(lg - mn);
            l = l * sc + ev;
            O.x = O.x * sc + ev * r3.x;
            O.y = O.y * sc + ev * r3.y;
            m = mn;
        }
    }

    float inv = (l > 0.f) ? 1.f / l : 0.f;
    float2 res = {O.x * inv + xd.x, O.y * inv + xd.y};
    out2[(long long)node * 64 + lane] = res;
}

extern "C" void kernel_launch(void* const* d_in, const int* in_sizes, int n_in,
                              void* d_out, int out_size, void* d_ws, size_t ws_size,
                              hipStream_t stream) {
    const float* x   = (const float*)d_in[0];
    const float* Wf  = (const float*)d_in[2];
    const float* Wb  = (const float*)d_in[3];
    const int* EI    = (const int*)d_in[5];
    const int* mask  = (const int*)d_in[7];
    // d_in[1] (W_alpha), d_in[4] (local_sess_avg), d_in[6] (batch) are dead:
    // alpha is constant within each softmax segment and cancels in the softmax.

    int N = in_sizes[6];             // 50000
    int E_total = in_sizes[5] / 2;   // 300000 (non-self + self loops)
    int E_NS = E_total - N;          // 250000
    int EE = E_total + E_NS;         // 550000 expanded edges

    const int* EI0 = EI;             // row 0: src (+ loops)
    const int* EI1 = EI + E_total;   // row 1: dst (+ loops)

    char* ws = (char*)d_ws;
    int* counts    = (int*)ws;                               // N
    int* cursor    = (int*)(ws + (size_t)N * 4);             // N  (contiguous w/ counts -> one memset)
    int* rowptrL   = (int*)(ws + (size_t)2 * N * 4);         // N
    int* blockSums = (int*)(ws + (size_t)3 * N * 4);         // 256
    int* csr       = (int*)(ws + (size_t)3 * N * 4 + 1024);  // EE

    hipMemsetAsync(counts, 0, (size_t)2 * N * 4, stream);    // counts + cursor

    const int BLK = 256;
    int edgeBlocks = (EE + BLK - 1) / BLK;
    int scanBlocks = (N + BLK - 1) / BLK;   // 196 <= 256, fits scan2's single block
    int nodeWaveBlocks = (N + 3) / 4;       // 4 waves (nodes) per 256-thread block

    count_kernel<<<edgeBlocks, BLK, 0, stream>>>(EI0, EI1, counts, E_total, E_NS);
    scan1_kernel<<<scanBlocks, BLK, 0, stream>>>(counts, rowptrL, blockSums, N);
    scan2_kernel<<<1, BLK, 0, stream>>>(blockSums, scanBlocks);
    fill_kernel<<<edgeBlocks, BLK, 0, stream>>>(EI0, EI1, rowptrL, blockSums, cursor, csr,
                                                E_total, E_NS);
    gather_kernel<<<nodeWaveBlocks, BLK, 0, stream>>>(
        (const float2*)x, (const float2*)Wf, (const float2*)Wb,
        rowptrL, blockSums, counts, csr, mask, (float2*)d_out, N);
}

// Round 4
// 184.894 us; speedup vs baseline: 3.9876x; 1.0671x over previous
//
#include <hip/hip_runtime.h>

#define NEG_SLOPE 0.01f

__device__ __forceinline__ float lrelu(float v) { return v > 0.f ? v : NEG_SLOPE * v; }

__device__ __forceinline__ float dot4(float4 a, float4 b) {
    return a.x * b.x + a.y * b.y + a.z * b.z + a.w * b.w;
}

// --- CSR build -------------------------------------------------------------

// 4 edges/thread via int4; region 1 = forward (dst=EI1), region 2 = reversed non-self (dst=EI0)
__global__ void count_kernel(const int* __restrict__ EI0, const int* __restrict__ EI1,
                             int* __restrict__ counts, int E_total, int E_NS) {
    int t = blockIdx.x * blockDim.x + threadIdx.x;
    int n1v = E_total >> 2, n0v = E_NS >> 2;
    if (t < n1v) {
        int4 d = ((const int4*)EI1)[t];
        atomicAdd(&counts[d.x], 1); atomicAdd(&counts[d.y], 1);
        atomicAdd(&counts[d.z], 1); atomicAdd(&counts[d.w], 1);
    } else if (t < n1v + n0v) {
        int4 d = ((const int4*)EI0)[t - n1v];
        atomicAdd(&counts[d.x], 1); atomicAdd(&counts[d.y], 1);
        atomicAdd(&counts[d.z], 1); atomicAdd(&counts[d.w], 1);
    } else if (t == n1v + n0v) {  // scalar tail (empty when E_total,E_NS %4==0)
        for (int e = E_total & ~3; e < E_total; e++) atomicAdd(&counts[EI1[e]], 1);
        for (int e = E_NS & ~3; e < E_NS; e++) atomicAdd(&counts[EI0[e]], 1);
    }
}

// block-local exclusive scan (256/block); rowptrL gets local-exclusive, blockSums gets block total
__global__ void scan1_kernel(const int* __restrict__ counts, int* __restrict__ rowptrL,
                             int* __restrict__ blockSums, int N) {
    __shared__ int tmp[256];
    int tid = threadIdx.x;
    int gid = blockIdx.x * 256 + tid;
    int v = (gid < N) ? counts[gid] : 0;
    tmp[tid] = v;
    __syncthreads();
#pragma unroll
    for (int off = 1; off < 256; off <<= 1) {
        int t = (tid >= off) ? tmp[tid - off] : 0;
        __syncthreads();
        tmp[tid] += t;
        __syncthreads();
    }
    if (gid < N) rowptrL[gid] = tmp[tid] - v;
    if (tid == 255) blockSums[blockIdx.x] = tmp[255];
}

// exclusive scan of block sums (nb <= 256), in place
__global__ void scan2_kernel(int* __restrict__ blockSums, int nb) {
    __shared__ int tmp[256];
    int tid = threadIdx.x;
    int v = (tid < nb) ? blockSums[tid] : 0;
    tmp[tid] = v;
    __syncthreads();
#pragma unroll
    for (int off = 1; off < 256; off <<= 1) {
        int t = (tid >= off) ? tmp[tid - off] : 0;
        __syncthreads();
        tmp[tid] += t;
        __syncthreads();
    }
    if (tid < nb) blockSums[tid] = tmp[tid] - v;
}

__device__ __forceinline__ void placeEdge(int s, int d, unsigned flag,
                                          const int* __restrict__ rowptrL,
                                          const int* __restrict__ blockSums,
                                          int* __restrict__ cursor, int* __restrict__ csr) {
    int pos = atomicAdd(&cursor[d], 1);
    csr[rowptrL[d] + blockSums[d >> 8] + pos] = (int)((unsigned)s | flag);
}

// 4 edges/thread; bit31 of csr entry = use-W_backward flag
__global__ void fill_kernel(const int* __restrict__ EI0, const int* __restrict__ EI1,
                            const int* __restrict__ rowptrL, const int* __restrict__ blockSums,
                            int* __restrict__ cursor, int* __restrict__ csr,
                            int E_total, int E_NS) {
    int t = blockIdx.x * blockDim.x + threadIdx.x;
    int n1v = E_total >> 2, n0v = E_NS >> 2;
    if (t < n1v) {
        int4 s = ((const int4*)EI0)[t];
        int4 d = ((const int4*)EI1)[t];
        placeEdge(s.x, d.x, 0u, rowptrL, blockSums, cursor, csr);
        placeEdge(s.y, d.y, 0u, rowptrL, blockSums, cursor, csr);
        placeEdge(s.z, d.z, 0u, rowptrL, blockSums, cursor, csr);
        placeEdge(s.w, d.w, 0u, rowptrL, blockSums, cursor, csr);
    } else if (t < n1v + n0v) {
        int u = t - n1v;
        int4 s = ((const int4*)EI1)[u];   // reversed: src=EI1, dst=EI0
        int4 d = ((const int4*)EI0)[u];
        placeEdge(s.x, d.x, 0x80000000u, rowptrL, blockSums, cursor, csr);
        placeEdge(s.y, d.y, 0x80000000u, rowptrL, blockSums, cursor, csr);
        placeEdge(s.z, d.z, 0x80000000u, rowptrL, blockSums, cursor, csr);
        placeEdge(s.w, d.w, 0x80000000u, rowptrL, blockSums, cursor, csr);
    } else if (t == n1v + n0v) {  // scalar tail
        for (int e = E_total & ~3; e < E_total; e++)
            placeEdge(EI0[e], EI1[e], 0u, rowptrL, blockSums, cursor, csr);
        for (int e = E_NS & ~3; e < E_NS; e++)
            placeEdge(EI1[e], EI0[e], 0x80000000u, rowptrL, blockSums, cursor, csr);
    }
}

// --- fused gather: 16 lanes/node, 4 nodes/wave, 2-edge ILP batches ----------
// online segment-softmax + weighted aggregation + residual; alpha cancels.
__global__ void gather_kernel(const float4* __restrict__ x4,
                              const float4* __restrict__ Wf4, const float4* __restrict__ Wb4,
                              const int* __restrict__ rowptrL, const int* __restrict__ blockSums,
                              const int* __restrict__ counts, const int* __restrict__ csr,
                              const int* __restrict__ mask,
                              float4* __restrict__ out4, int N) {
    int tid = blockIdx.x * blockDim.x + threadIdx.x;
    int node = tid >> 4;          // one node per 16 lanes
    int sub = threadIdx.x & 15;   // lane within the 16-group
    bool active = (node < N);
    int nodeSafe = active ? node : 0;

    long long base = (long long)nodeSafe * 32;   // row in float4 units
    float4 xda = x4[base + sub];
    float4 xdb = x4[base + 16 + sub];
    float4 wfa = Wf4[sub], wfb = Wf4[16 + sub];
    float4 wba = Wb4[sub], wbb = Wb4[16 + sub];
    float4 yfa = {xda.x * wfa.x, xda.y * wfa.y, xda.z * wfa.z, xda.w * wfa.w};
    float4 yfb = {xdb.x * wfb.x, xdb.y * wfb.y, xdb.z * wfb.z, xdb.w * wfb.w};
    float4 yba = {xda.x * wba.x, xda.y * wba.y, xda.z * wba.z, xda.w * wba.w};
    float4 ybb = {xdb.x * wbb.x, xdb.y * wbb.y, xdb.z * wbb.z, xdb.w * wbb.w};

    int cnt = active ? counts[node] : 0;
    int beg = active ? (rowptrL[node] + blockSums[node >> 8]) : 0;

    // max count across the wave's 4 groups (uniform within group)
    int cm = cnt;
    cm = max(cm, __shfl_xor(cm, 16, 64));
    cm = max(cm, __shfl_xor(cm, 32, 64));

    float m = -INFINITY, l = 0.f;
    float4 Oa = {0.f, 0.f, 0.f, 0.f}, Ob = {0.f, 0.f, 0.f, 0.f};

    for (int i = 0; i < cm; i += 2) {
        bool v0 = (i < cnt), v1 = (i + 1 < cnt);
        int e0 = v0 ? csr[beg + i] : 0;
        int e1 = v1 ? csr[beg + i + 1] : 0;
        long long s0 = (long long)(e0 & 0x7fffffff) * 32;
        long long s1 = (long long)(e1 & 0x7fffffff) * 32;
        // 4 outstanding 16B loads per lane
        float4 r0a = x4[s0 + sub], r0b = x4[s0 + 16 + sub];
        float4 r1a = x4[s1 + sub], r1b = x4[s1 + 16 + sub];
        bool f0 = (e0 < 0), f1 = (e1 < 0);

        float p0 = dot4(r0a, f0 ? yba : yfa) + dot4(r0b, f0 ? ybb : yfb);
        float p1 = dot4(r1a, f1 ? yba : yfa) + dot4(r1b, f1 ? ybb : yfb);
        // 4-step reduce within 16 lanes, 2 interleaved chains
#pragma unroll
        for (int sh = 1; sh < 16; sh <<= 1) {
            p0 += __shfl_xor(p0, sh, 64);
            p1 += __shfl_xor(p1, sh, 64);
        }

        if (v0) {
            float lg = lrelu(p0);
            float mn = fmaxf(m, lg);
            float sc = __expf(m - mn), ev = __expf(lg - mn);
            l = l * sc + ev;
            Oa.x = Oa.x * sc + ev * r0a.x; Oa.y = Oa.y * sc + ev * r0a.y;
            Oa.z = Oa.z * sc + ev * r0a.z; Oa.w = Oa.w * sc + ev * r0a.w;
            Ob.x = Ob.x * sc + ev * r0b.x; Ob.y = Ob.y * sc + ev * r0b.y;
            Ob.z = Ob.z * sc + ev * r0b.z; Ob.w = Ob.w * sc + ev * r0b.w;
            m = mn;
        }
        if (v1) {
            float lg = lrelu(p1);
            float mn = fmaxf(m, lg);
            float sc = __expf(m - mn), ev = __expf(lg - mn);
            l = l * sc + ev;
            Oa.x = Oa.x * sc + ev * r1a.x; Oa.y = Oa.y * sc + ev * r1a.y;
            Oa.z = Oa.z * sc + ev * r1a.z; Oa.w = Oa.w * sc + ev * r1a.w;
            Ob.x = Ob.x * sc + ev * r1b.x; Ob.y = Ob.y * sc + ev * r1b.y;
            Ob.z = Ob.z * sc + ev * r1b.z; Ob.w = Ob.w * sc + ev * r1b.w;
            m = mn;
        }
    }

    if (active) {
        float inv = (l > 0.f) ? 1.f / l : 0.f;
        float4 ra, rb;
        if (mask[node] == 1) {
            ra = {Oa.x * inv + xda.x, Oa.y * inv + xda.y, Oa.z * inv + xda.z, Oa.w * inv + xda.w};
            rb = {Ob.x * inv + xdb.x, Ob.y * inv + xdb.y, Ob.z * inv + xdb.z, Ob.w * inv + xdb.w};
        } else {
            ra = {2.f * xda.x, 2.f * xda.y, 2.f * xda.z, 2.f * xda.w};
            rb = {2.f * xdb.x, 2.f * xdb.y, 2.f * xdb.z, 2.f * xdb.w};
        }
        out4[base + sub] = ra;
        out4[base + 16 + sub] = rb;
    }
}

extern "C" void kernel_launch(void* const* d_in, const int* in_sizes, int n_in,
                              void* d_out, int out_size, void* d_ws, size_t ws_size,
                              hipStream_t stream) {
    const float* x   = (const float*)d_in[0];
    const float* Wf  = (const float*)d_in[2];
    const float* Wb  = (const float*)d_in[3];
    const int* EI    = (const int*)d_in[5];
    const int* mask  = (const int*)d_in[7];
    // d_in[1] (W_alpha), d_in[4] (local_sess_avg), d_in[6] (batch) are dead:
    // alpha is constant within each softmax segment and cancels in the softmax.

    int N = in_sizes[6];             // 50000
    int E_total = in_sizes[5] / 2;   // 300000 (non-self + self loops)
    int E_NS = E_total - N;          // 250000
    int EE = E_total + E_NS;         // 550000 expanded edges

    const int* EI0 = EI;             // row 0: src (+ loops)
    const int* EI1 = EI + E_total;   // row 1: dst (+ loops)

    char* ws = (char*)d_ws;
    int* counts    = (int*)ws;                               // N
    int* cursor    = (int*)(ws + (size_t)N * 4);             // N  (contiguous -> one memset)
    int* rowptrL   = (int*)(ws + (size_t)2 * N * 4);         // N
    int* blockSums = (int*)(ws + (size_t)3 * N * 4);         // 256
    int* csr       = (int*)(ws + (size_t)3 * N * 4 + 1024);  // EE

    hipMemsetAsync(counts, 0, (size_t)2 * N * 4, stream);    // counts + cursor

    const int BLK = 256;
    int edgeVecThreads = (E_total >> 2) + (E_NS >> 2) + 1;   // +1 tail thread
    int edgeVecBlocks = (edgeVecThreads + BLK - 1) / BLK;
    int scanBlocks = (N + BLK - 1) / BLK;   // 196 <= 256, fits scan2's single block
    int nodeBlocks = (N + 15) / 16;         // 16 nodes per 256-thread block

    count_kernel<<<edgeVecBlocks, BLK, 0, stream>>>(EI0, EI1, counts, E_total, E_NS);
    scan1_kernel<<<scanBlocks, BLK, 0, stream>>>(counts, rowptrL, blockSums, N);
    scan2_kernel<<<1, BLK, 0, stream>>>(blockSums, scanBlocks);
    fill_kernel<<<edgeVecBlocks, BLK, 0, stream>>>(EI0, EI1, rowptrL, blockSums, cursor, csr,
                                                   E_total, E_NS);
    gather_kernel<<<nodeBlocks, BLK, 0, stream>>>(
        (const float4*)x, (const float4*)Wf, (const float4*)Wb,
        rowptrL, blockSums, counts, csr, mask, (float4*)d_out, N);
}